// Round 6
// baseline (779.904 us; speedup 1.0000x reference)
//
#include <hip/hip_runtime.h>
#include <hip/hip_bf16.h>

// Problem: out[M=4096][N=16384] = x[M][K=4096] @ (W[N][K] * scale[N/128][K/128])^T + bias[N]
#define M_DIM 4096
#define N_DIM 16384
#define K_DIM 4096

typedef __bf16 bf16x8 __attribute__((ext_vector_type(8)));
typedef float f32x4 __attribute__((ext_vector_type(4)));

__device__ __forceinline__ void gload16(const void* g, void* l) {
    __builtin_amdgcn_global_load_lds((__attribute__((address_space(1))) void*)g,
                                     (__attribute__((address_space(3))) void*)l, 16, 0, 0);
}

// ---------- prepass 1: x fp32 -> bf16 ----------
__global__ __launch_bounds__(256) void cvt_x_kernel(const float* __restrict__ x,
                                                    __hip_bfloat16* __restrict__ out,
                                                    int ngroups) {
    int i = blockIdx.x * blockDim.x + threadIdx.x;
    int stride = gridDim.x * blockDim.x;
    for (; i < ngroups; i += stride) {
        const float4* p = (const float4*)(x + (size_t)i * 8);
        float4 v0 = p[0];
        float4 v1 = p[1];
        bf16x8 r;
        r[0] = (__bf16)v0.x; r[1] = (__bf16)v0.y; r[2] = (__bf16)v0.z; r[3] = (__bf16)v0.w;
        r[4] = (__bf16)v1.x; r[5] = (__bf16)v1.y; r[6] = (__bf16)v1.z; r[7] = (__bf16)v1.w;
        *(bf16x8*)(out + (size_t)i * 8) = r;
    }
}

// ---------- prepass 2: W fp32 * blockscale -> bf16 ----------
__global__ __launch_bounds__(256) void dequant_w_kernel(const float* __restrict__ w,
                                                        const float* __restrict__ scale,
                                                        __hip_bfloat16* __restrict__ out) {
    const int ngroups = N_DIM * (K_DIM / 8);
    int i = blockIdx.x * blockDim.x + threadIdx.x;
    int stride = gridDim.x * blockDim.x;
    for (; i < ngroups; i += stride) {
        int row = i >> 9;
        int cg  = i & 511;
        float s = scale[(row >> 7) * (K_DIM / 128) + (cg >> 4)];
        const float4* p = (const float4*)(w + (size_t)i * 8);
        float4 v0 = p[0];
        float4 v1 = p[1];
        bf16x8 r;
        r[0] = (__bf16)(v0.x * s); r[1] = (__bf16)(v0.y * s);
        r[2] = (__bf16)(v0.z * s); r[3] = (__bf16)(v0.w * s);
        r[4] = (__bf16)(v1.x * s); r[5] = (__bf16)(v1.y * s);
        r[6] = (__bf16)(v1.z * s); r[7] = (__bf16)(v1.w * s);
        *(bf16x8*)(out + (size_t)i * 8) = r;
    }
}

// ---------- main GEMM: 256x256, BK=64, 8 waves, intra-wave pipelined ----------
// Read groups per K-tile (per wave): R0={a_lo,b}@c0 (8), R1=a_hi@c0 (4),
// R2={a_lo,b}@c1 (8), R3=a_hi@c1 (4). Clusters: C0(aE,bL) C1(aO,bL)
// C2(aE,bH) C3(aO,bH). Schedule: reads run ONE cluster AHEAD:
//   P0: issue R1; lgkmcnt(4)[=R0 done]; C0
//   P1: issue R2; lgkmcnt(8)[=R1 done]; C1
//   P2: issue R3; lgkmcnt(4)[=R2 done]; C2
//   P3: vmcnt(0); BAR1; issue R0(next tile, other buf); lgkmcnt(8)[=R3 done];
//       BAR2; stage tile t+2 -> buf[cur]; C3
// In-order DS retire makes counted lgkmcnt exact. Only 2 barriers/K-tile:
//   BAR1: every wave retired its own stages (vmcnt 0) -> tile t+1 resident
//         before any wave reads it (stages were issued a full iter ago => no
//         actual wait in steady state).
//   BAR2: every wave passed lgkmcnt(8) => its R3 (last reads of tile t) done
//         -> safe to overwrite buf[cur] with tile t+2.
// No P0-P2 barriers: waves drift; LDS pipe (reads) and matrix pipe (MFMA)
// run concurrently both intra-wave (read-ahead) and inter-wave (drift).
__global__ __launch_bounds__(512, 2)
void gemm_bf16_kernel(const __hip_bfloat16* __restrict__ A,   // [M][K] bf16
                      const __hip_bfloat16* __restrict__ Bw,  // [N][K] bf16
                      const float* __restrict__ bias,
                      float* __restrict__ C) {                // [M][N] fp32
    constexpr int Mtiles = M_DIM / 256;            // 16
    constexpr int Ntiles = N_DIM / 256;            // 64
    constexpr int nwg = Mtiles * Ntiles;           // 1024 (div by 8)
    constexpr int NT = K_DIM / 64;                 // 64 K-tiles

    int bid = blockIdx.x;
    int swz = (bid & 7) * (nwg >> 3) + (bid >> 3);   // bijective XCD swizzle
    int bm = swz % Mtiles;
    int bn = swz / Mtiles;

    __shared__ __align__(16) __hip_bfloat16 sA[2][256 * 64];   // 64 KiB
    __shared__ __align__(16) __hip_bfloat16 sB[2][256 * 64];   // 64 KiB

    const int t = threadIdx.x;
    const int l = t & 63;
    const int w = t >> 6;        // wave 0..7
    const int wm = w >> 2;       // 0..1  (M half)
    const int wn = w & 3;        // 0..3  (N quarter)

    const int lr = l & 15;
    const int lk = l >> 4;
    const int rx = (lr & 7) << 3;          // read-side element-col XOR

    // staging (rule #21): linear LDS dest, pre-swizzled global source col.
    const int srow = w * 8 + (l >> 3);
    const int scol = ((l & 7) ^ (l >> 3)) << 3;

    const size_t K = K_DIM;
    const __hip_bfloat16* aB = A  + (size_t)(bm * 256) * K + scol;
    const __hip_bfloat16* bB = Bw + (size_t)(bn * 256) * K + scol;

    f32x4 acc[8][4] = {};

    const int c0 = (lk * 8) ^ rx;
    const int c1 = (32 + lk * 8) ^ rx;
    const int arow = (wm * 128 + lr) * 64;
    const int brow = (wn * 64 + lr) * 64;

#define STAGE(bufidx, gA, gBp)                                                  \
    do {                                                                        \
        char* la_ = (char*)&sA[(bufidx)][0] + w * 1024;                         \
        char* lb_ = (char*)&sB[(bufidx)][0] + w * 1024;                         \
        _Pragma("unroll")                                                       \
        for (int j = 0; j < 4; ++j) {                                           \
            gload16((gA) + (size_t)(j * 64 + srow) * K, la_ + j * 8192);        \
            gload16((gBp) + (size_t)(j * 64 + srow) * K, lb_ + j * 8192);       \
        }                                                                       \
    } while (0)

#define CLUSTER(af, bf, off)                                                    \
    do {                                                                        \
        __builtin_amdgcn_s_setprio(1);                                          \
        _Pragma("unroll")                                                       \
        for (int mi = 0; mi < 4; ++mi)                                          \
            _Pragma("unroll")                                                   \
            for (int ni = 0; ni < 4; ++ni)                                      \
                acc[(off) + mi][ni] = __builtin_amdgcn_mfma_f32_16x16x32_bf16(  \
                    af[mi], bf[ni], acc[(off) + mi][ni], 0, 0, 0);              \
        __builtin_amdgcn_s_setprio(0);                                          \
    } while (0)

    bf16x8 aE[4], aO[4], bL[4], bH[4];
    const __hip_bfloat16* pa;
    const __hip_bfloat16* pb;

    // prologue: stage tiles 0,1; wait tile0; read R0(tile0)
    STAGE(0, aB, bB);
    STAGE(1, aB + 64, bB + 64);
    asm volatile("s_waitcnt vmcnt(8)" ::: "memory");
    __builtin_amdgcn_sched_barrier(0);
    __builtin_amdgcn_s_barrier();
    __builtin_amdgcn_sched_barrier(0);
    pa = &sA[0][0];
    pb = &sB[0][0];
    #pragma unroll
    for (int i = 0; i < 4; ++i) {
        aE[i] = *(const bf16x8*)(pa + arow + i * 1024 + c0);
        bL[i] = *(const bf16x8*)(pb + brow + i * 1024 + c0);
    }
    __builtin_amdgcn_sched_barrier(0);

    #pragma unroll 1
    for (int kt = 0; kt < NT; ++kt) {
        const int cur = kt & 1;
        pa = &sA[cur][0];
        pb = &sB[cur][0];
        const __hip_bfloat16* paN = &sA[cur ^ 1][0];
        const __hip_bfloat16* pbN = &sB[cur ^ 1][0];

        // ---- P0: issue R1 (aO <- a_hi@c0); wait R0; C0(aE,bL) ----
        #pragma unroll
        for (int i = 0; i < 4; ++i)
            aO[i] = *(const bf16x8*)(pa + arow + 4096 + i * 1024 + c0);
        __builtin_amdgcn_sched_barrier(0);
        asm volatile("s_waitcnt lgkmcnt(4)" ::: "memory");
        __builtin_amdgcn_sched_barrier(0);
        CLUSTER(aE, bL, 0);
        __builtin_amdgcn_sched_barrier(0);

        // ---- P1: issue R2 (aE <- a_lo@c1, bH <- b@c1); wait R1; C1(aO,bL) ----
        #pragma unroll
        for (int i = 0; i < 4; ++i) {
            aE[i] = *(const bf16x8*)(pa + arow + i * 1024 + c1);
            bH[i] = *(const bf16x8*)(pb + brow + i * 1024 + c1);
        }
        __builtin_amdgcn_sched_barrier(0);
        asm volatile("s_waitcnt lgkmcnt(8)" ::: "memory");
        __builtin_amdgcn_sched_barrier(0);
        CLUSTER(aO, bL, 4);
        __builtin_amdgcn_sched_barrier(0);

        // ---- P2: issue R3 (aO <- a_hi@c1); wait R2; C2(aE,bH) ----
        #pragma unroll
        for (int i = 0; i < 4; ++i)
            aO[i] = *(const bf16x8*)(pa + arow + 4096 + i * 1024 + c1);
        __builtin_amdgcn_sched_barrier(0);
        asm volatile("s_waitcnt lgkmcnt(4)" ::: "memory");
        __builtin_amdgcn_sched_barrier(0);
        CLUSTER(aE, bH, 0);
        __builtin_amdgcn_sched_barrier(0);

        // ---- P3: sync point; read R0(next); wait R3; stage t+2; C3(aO,bH) ----
        if (kt + 1 < NT) {
            asm volatile("s_waitcnt vmcnt(0)" ::: "memory");   // own stages of t+1 retired (issued 1 iter ago: no-wait)
            __builtin_amdgcn_sched_barrier(0);
            __builtin_amdgcn_s_barrier();                       // BAR1: tile t+1 resident for all
            __builtin_amdgcn_sched_barrier(0);
            #pragma unroll
            for (int i = 0; i < 4; ++i) {
                aE[i] = *(const bf16x8*)(paN + arow + i * 1024 + c0);
                bL[i] = *(const bf16x8*)(pbN + brow + i * 1024 + c0);
            }
            __builtin_amdgcn_sched_barrier(0);
            asm volatile("s_waitcnt lgkmcnt(8)" ::: "memory");  // R3 done (last reads of tile t)
            __builtin_amdgcn_sched_barrier(0);
            __builtin_amdgcn_s_barrier();                       // BAR2: all waves done reading tile t
            __builtin_amdgcn_sched_barrier(0);
            if (kt + 2 < NT) {
                STAGE(cur, aB + (kt + 2) * 64, bB + (kt + 2) * 64);
            }
            __builtin_amdgcn_sched_barrier(0);
        } else {
            asm volatile("s_waitcnt lgkmcnt(0)" ::: "memory");
            __builtin_amdgcn_sched_barrier(0);
        }
        CLUSTER(aO, bH, 4);
        __builtin_amdgcn_sched_barrier(0);
    }
#undef STAGE
#undef CLUSTER

    // epilogue: C/D layout col=lane&15, row=(lane>>4)*4+reg  [m89-verified]
    const int crow0 = bm * 256 + wm * 128;
    const int ccol0 = bn * 256 + wn * 64;
    #pragma unroll
    for (int ni = 0; ni < 4; ++ni) {
        int col = ccol0 + ni * 16 + lr;
        float bv = bias[col];
        #pragma unroll
        for (int mi = 0; mi < 8; ++mi) {
            int rbase = crow0 + mi * 16 + lk * 4;
            #pragma unroll
            for (int j = 0; j < 4; ++j) {
                C[(size_t)(rbase + j) * N_DIM + col] = acc[mi][ni][j] + bv;
            }
        }
    }
}

// ---------- fallback (ws too small): fp32 LDS-tiled, correct but slow ----------
__global__ __launch_bounds__(256)
void gemm_fallback(const float* __restrict__ X, const float* __restrict__ W,
                   const float* __restrict__ scale, const float* __restrict__ bias,
                   float* __restrict__ C) {
    int bm = blockIdx.x % (M_DIM / 64);
    int bn = blockIdx.x / (M_DIM / 64);
    __shared__ float sA[64][33];
    __shared__ float sB[64][33];
    int t = threadIdx.x;
    int tx = t & 15, ty = t >> 4;
    float acc[4][4] = {};
    for (int kt = 0; kt < K_DIM / 32; ++kt) {
        float s = scale[(bn >> 1) * (K_DIM / 128) + (kt >> 2)];
        #pragma unroll
        for (int i = 0; i < 8; ++i) {
            int idx = t + i * 256;
            int r = idx >> 5, c = idx & 31;
            sA[r][c] = X[(size_t)(bm * 64 + r) * K_DIM + kt * 32 + c];
            sB[r][c] = W[(size_t)(bn * 64 + r) * K_DIM + kt * 32 + c] * s;
        }
        __syncthreads();
        #pragma unroll
        for (int k = 0; k < 32; ++k) {
            float a[4], b[4];
            #pragma unroll
            for (int i = 0; i < 4; ++i) a[i] = sA[ty * 4 + i][k];
            #pragma unroll
            for (int j = 0; j < 4; ++j) b[j] = sB[tx * 4 + j][k];
            #pragma unroll
            for (int i = 0; i < 4; ++i)
                #pragma unroll
                for (int j = 0; j < 4; ++j) acc[i][j] += a[i] * b[j];
        }
        __syncthreads();
    }
    #pragma unroll
    for (int i = 0; i < 4; ++i)
        #pragma unroll
        for (int j = 0; j < 4; ++j) {
            int row = bm * 64 + ty * 4 + i;
            int col = bn * 64 + tx * 4 + j;
            C[(size_t)row * N_DIM + col] = acc[i][j] + bias[col];
        }
}

extern "C" void kernel_launch(void* const* d_in, const int* in_sizes, int n_in,
                              void* d_out, int out_size, void* d_ws, size_t ws_size,
                              hipStream_t stream) {
    const float* x     = (const float*)d_in[0];   // [2,2048,4096]
    const float* wgt   = (const float*)d_in[1];   // [16384,4096]
    const float* scale = (const float*)d_in[2];   // [128,32]
    const float* bias  = (const float*)d_in[3];   // [16384]
    float* out = (float*)d_out;                   // [2,2048,16384]

    const size_t need = ((size_t)M_DIM * K_DIM + (size_t)N_DIM * K_DIM) * sizeof(__hip_bfloat16);
    if (ws_size >= need) {
        __hip_bfloat16* xbf = (__hip_bfloat16*)d_ws;
        __hip_bfloat16* wbf = xbf + (size_t)M_DIM * K_DIM;
        cvt_x_kernel<<<2048, 256, 0, stream>>>(x, xbf, M_DIM * K_DIM / 8);
        dequant_w_kernel<<<4096, 256, 0, stream>>>(wgt, scale, wbf);
        gemm_bf16_kernel<<<(M_DIM / 256) * (N_DIM / 256), 512, 0, stream>>>(xbf, wbf, bias, out);
    } else {
        gemm_fallback<<<(M_DIM / 64) * (N_DIM / 64), 256, 0, stream>>>(x, wgt, scale, bias, out);
    }
}

// Round 7
// 710.768 us; speedup vs baseline: 1.0973x; 1.0973x over previous
//
#include <hip/hip_runtime.h>
#include <hip/hip_bf16.h>

// Problem: out[M=4096][N=16384] = x[M][K=4096] @ (W[N][K] * scale[N/128][K/128])^T + bias[N]
#define M_DIM 4096
#define N_DIM 16384
#define K_DIM 4096

typedef __bf16 bf16x8 __attribute__((ext_vector_type(8)));
typedef float f32x4 __attribute__((ext_vector_type(4)));

__device__ __forceinline__ void gload16(const void* g, void* l) {
    __builtin_amdgcn_global_load_lds((__attribute__((address_space(1))) void*)g,
                                     (__attribute__((address_space(3))) void*)l, 16, 0, 0);
}

// ---------- prepass 1: x fp32 -> bf16 ----------
__global__ __launch_bounds__(256) void cvt_x_kernel(const float* __restrict__ x,
                                                    __hip_bfloat16* __restrict__ out,
                                                    int ngroups) {
    int i = blockIdx.x * blockDim.x + threadIdx.x;
    int stride = gridDim.x * blockDim.x;
    for (; i < ngroups; i += stride) {
        const float4* p = (const float4*)(x + (size_t)i * 8);
        float4 v0 = p[0];
        float4 v1 = p[1];
        bf16x8 r;
        r[0] = (__bf16)v0.x; r[1] = (__bf16)v0.y; r[2] = (__bf16)v0.z; r[3] = (__bf16)v0.w;
        r[4] = (__bf16)v1.x; r[5] = (__bf16)v1.y; r[6] = (__bf16)v1.z; r[7] = (__bf16)v1.w;
        *(bf16x8*)(out + (size_t)i * 8) = r;
    }
}

// ---------- prepass 2: W fp32 * blockscale -> bf16 ----------
__global__ __launch_bounds__(256) void dequant_w_kernel(const float* __restrict__ w,
                                                        const float* __restrict__ scale,
                                                        __hip_bfloat16* __restrict__ out) {
    const int ngroups = N_DIM * (K_DIM / 8);
    int i = blockIdx.x * blockDim.x + threadIdx.x;
    int stride = gridDim.x * blockDim.x;
    for (; i < ngroups; i += stride) {
        int row = i >> 9;
        int cg  = i & 511;
        float s = scale[(row >> 7) * (K_DIM / 128) + (cg >> 4)];
        const float4* p = (const float4*)(w + (size_t)i * 8);
        float4 v0 = p[0];
        float4 v1 = p[1];
        bf16x8 r;
        r[0] = (__bf16)(v0.x * s); r[1] = (__bf16)(v0.y * s);
        r[2] = (__bf16)(v0.z * s); r[3] = (__bf16)(v0.w * s);
        r[4] = (__bf16)(v1.x * s); r[5] = (__bf16)(v1.y * s);
        r[6] = (__bf16)(v1.z * s); r[7] = (__bf16)(v1.w * s);
        *(bf16x8*)(out + (size_t)i * 8) = r;
    }
}

// ---------- main GEMM: 256x256, BK=64, 8 waves, m201 8-phase schedule ----------
// Iteration handles 2 K-tiles: t=2p (buf0), u=2p+1 (buf1). Per phase:
//   { ds_reads (12|4|8|0); stage ONE half-tile (2 gloads); [lgkm8 if 12 reads];
//     BAR; lgkm0; setprio1; 16 MFMA; setprio0; BAR }
// Quadrant order per K-tile: (00)(01)(10)(11) => A-frags fully read after the
// tile's 3rd phase, B-frags after its 2nd.
// Stage slots + safety (overwrite target dead = last reader's lgkm0 is before
// an intervening barrier):
//   P1: buf1.A0<-u.A0   [buf1.A last read prev-iter P7; P8-end bar between]
//   P2: buf1.A1<-u.A1   [same]
//   P3: buf0.B0<-t2.B0  [buf0.B reads end P2 (b01@P1,b23@P2); P2-end bar]
//   P4: buf0.B1<-t2.B1 + vmcnt(4): keep 2 newest halves (P3,P4) => retires
//       P1,P2 (u.A) and prev P7,P8 (u.B) -> buf1 resident for P5-P8. BAR.
//   P5: buf0.A0<-t2.A0  [buf0.A reads end P3 (a03@P1,a47@P3); P3-end bar]
//   P6: buf0.A1<-t2.A1
//   P7: buf1.B0<-t3.B0  [buf1.B reads end P6]
//   P8: buf1.B1<-t3.B1 + vmcnt(4): keep P7,P8 => retires P3-P6 (t2 full)
//       -> buf0 resident for next-P1. BAR.
// vmcnt never drains to 0 in steady loop; last iteration peeled to vmcnt(0).
__global__ __launch_bounds__(512, 2)
void gemm_bf16_kernel(const __hip_bfloat16* __restrict__ A,   // [M][K] bf16
                      const __hip_bfloat16* __restrict__ Bw,  // [N][K] bf16
                      const float* __restrict__ bias,
                      float* __restrict__ C) {                // [M][N] fp32
    constexpr int Mtiles = M_DIM / 256;            // 16
    constexpr int Ntiles = N_DIM / 256;            // 64
    constexpr int nwg = Mtiles * Ntiles;           // 1024 (div by 8)

    int bid = blockIdx.x;
    int swz = (bid & 7) * (nwg >> 3) + (bid >> 3);   // bijective XCD swizzle
    int bm = swz % Mtiles;
    int bn = swz / Mtiles;

    __shared__ __align__(16) __hip_bfloat16 sA[2][256 * 64];   // 64 KiB
    __shared__ __align__(16) __hip_bfloat16 sB[2][256 * 64];   // 64 KiB

    const int t = threadIdx.x;
    const int l = t & 63;
    const int w = t >> 6;        // wave 0..7
    const int wm = w >> 2;       // 0..1  (M half)
    const int wn = w & 3;        // 0..3  (N quarter)

    const int lr = l & 15;
    const int lk = l >> 4;
    const int rx = (lr & 7) << 3;          // read-side element-col XOR

    // staging (rule #21): linear LDS dest, pre-swizzled global source col.
    const int srow = w * 8 + (l >> 3);
    const int scol = ((l & 7) ^ (l >> 3)) << 3;

    const size_t K = K_DIM;
    const __hip_bfloat16* aB = A  + (size_t)(bm * 256) * K + scol;
    const __hip_bfloat16* bB = Bw + (size_t)(bn * 256) * K + scol;

    f32x4 acc[8][4] = {};

    const int c0 = (lk * 8) ^ rx;
    const int c1 = (32 + lk * 8) ^ rx;
    const int arow = (wm * 128 + lr) * 64;
    const int brow = (wn * 64 + lr) * 64;

    char* A0b = (char*)&sA[0][0] + w * 1024;   // + half*16384 + j*8192 (+l*16 hw)
    char* B0b = (char*)&sB[0][0] + w * 1024;
    char* A1b = (char*)&sA[1][0] + w * 1024;
    char* B1b = (char*)&sB[1][0] + w * 1024;

// stage one half-tile (128 rows x 64 cols): 2 gloads/thread
#define SH(lbase, gptr)                                                         \
    do {                                                                        \
        gload16((gptr) + (size_t)srow * K, (lbase));                            \
        gload16((gptr) + (size_t)(64 + srow) * K, (lbase) + 8192);              \
    } while (0)

#define RD_A(dst, off)                                                          \
    _Pragma("unroll")                                                           \
    for (int mi = 0; mi < 4; ++mi) {                                            \
        dst[mi][0] = *(const bf16x8*)(pa_ + arow + (off) + mi * 1024 + c0);     \
        dst[mi][1] = *(const bf16x8*)(pa_ + arow + (off) + mi * 1024 + c1);     \
    }

#define RD_B(dst, off)                                                          \
    _Pragma("unroll")                                                           \
    for (int ni = 0; ni < 2; ++ni) {                                            \
        dst[ni][0] = *(const bf16x8*)(pb_ + brow + (off) + ni * 1024 + c0);     \
        dst[ni][1] = *(const bf16x8*)(pb_ + brow + (off) + ni * 1024 + c1);     \
    }

#define MM(mo, no, af, bf)                                                      \
    do {                                                                        \
        __builtin_amdgcn_s_setprio(1);                                          \
        _Pragma("unroll")                                                       \
        for (int s = 0; s < 2; ++s)                                             \
            _Pragma("unroll")                                                   \
            for (int mi = 0; mi < 4; ++mi)                                      \
                _Pragma("unroll")                                               \
                for (int ni = 0; ni < 2; ++ni)                                  \
                    acc[(mo) + mi][(no) + ni] =                                 \
                        __builtin_amdgcn_mfma_f32_16x16x32_bf16(                \
                            af[mi][s], bf[ni][s], acc[(mo) + mi][(no) + ni],    \
                            0, 0, 0);                                           \
        __builtin_amdgcn_s_setprio(0);                                          \
    } while (0)

#define BAR()  __builtin_amdgcn_s_barrier()
#define SBAR() __builtin_amdgcn_sched_barrier(0)
#define LGKM0() do { asm volatile("s_waitcnt lgkmcnt(0)" ::: "memory"); SBAR(); } while (0)

    bf16x8 a03[4][2], a47[4][2], b01[2][2], b23[2][2];

    // prologue: tile0 full -> buf0; tile1 B halves -> buf1.B ; keep newest 4
    SH(A0b, aB);  SH(A0b + 16384, aB + (size_t)128 * K);
    SH(B0b, bB);  SH(B0b + 16384, bB + (size_t)128 * K);
    SH(B1b, bB + 64);  SH(B1b + 16384, bB + 64 + (size_t)128 * K);
    asm volatile("s_waitcnt vmcnt(4)" ::: "memory");   // tile0 resident
    SBAR();
    BAR();

    #pragma unroll 1
    for (int p = 0; p < 32; ++p) {
        const bool last = (p == 31);
        const __hip_bfloat16* gAu  = aB + (size_t)(2 * p + 1) * 64;
        const __hip_bfloat16* gAt2 = aB + (size_t)(2 * p + 2) * 64;
        const __hip_bfloat16* gBt2 = bB + (size_t)(2 * p + 2) * 64;
        const __hip_bfloat16* gBt3 = bB + (size_t)(2 * p + 3) * 64;
        const __hip_bfloat16* pa_;
        const __hip_bfloat16* pb_;

        // ================= K-tile t = 2p (buf0) =================
        pa_ = &sA[0][0]; pb_ = &sB[0][0];
        // --- P1: reads a03,b01 (12); stage buf1.A0<-u ---
        RD_A(a03, 0); RD_B(b01, 0);
        SH(A1b, gAu);
        SBAR();
        asm volatile("s_waitcnt lgkmcnt(8)" ::: "memory");
        BAR();
        LGKM0();
        MM(0, 0, a03, b01);
        SBAR(); BAR();
        // --- P2: reads b23 (4); stage buf1.A1<-u ---
        RD_B(b23, 2048);
        SH(A1b + 16384, gAu + (size_t)128 * K);
        SBAR(); BAR();
        LGKM0();
        MM(0, 2, a03, b23);
        SBAR(); BAR();
        // --- P3: reads a47 (8); stage buf0.B0<-t2 ---
        RD_A(a47, 4096);
        if (!last) SH(B0b, gBt2);
        SBAR(); BAR();
        LGKM0();
        MM(4, 0, a47, b01);
        SBAR(); BAR();
        // --- P4: stage buf0.B1<-t2; vmcnt(4) -> buf1 resident ---
        if (!last) {
            SH(B0b + 16384, gBt2 + (size_t)128 * K);
            asm volatile("s_waitcnt vmcnt(4)" ::: "memory");
        } else {
            asm volatile("s_waitcnt vmcnt(0)" ::: "memory");
        }
        SBAR(); BAR();
        MM(4, 2, a47, b23);
        SBAR(); BAR();

        // ================= K-tile u = 2p+1 (buf1) =================
        pa_ = &sA[1][0]; pb_ = &sB[1][0];
        // --- P5: reads a03,b01 (12); stage buf0.A0<-t2 ---
        RD_A(a03, 0); RD_B(b01, 0);
        if (!last) SH(A0b, gAt2);
        SBAR();
        asm volatile("s_waitcnt lgkmcnt(8)" ::: "memory");
        BAR();
        LGKM0();
        MM(0, 0, a03, b01);
        SBAR(); BAR();
        // --- P6: reads b23 (4); stage buf0.A1<-t2 ---
        RD_B(b23, 2048);
        if (!last) SH(A0b + 16384, gAt2 + (size_t)128 * K);
        SBAR(); BAR();
        LGKM0();
        MM(0, 2, a03, b23);
        SBAR(); BAR();
        // --- P7: reads a47 (8); stage buf1.B0<-t3 ---
        RD_A(a47, 4096);
        if (!last) SH(B1b, gBt3);
        SBAR(); BAR();
        LGKM0();
        MM(4, 0, a47, b01);
        SBAR(); BAR();
        // --- P8: stage buf1.B1<-t3; vmcnt(4) -> buf0 (t2) resident ---
        if (!last) {
            SH(B1b + 16384, gBt3 + (size_t)128 * K);
            asm volatile("s_waitcnt vmcnt(4)" ::: "memory");
        }
        SBAR(); BAR();
        MM(4, 2, a47, b23);
        SBAR();
        if (!last) BAR();
    }
#undef SH
#undef RD_A
#undef RD_B
#undef MM
#undef BAR
#undef SBAR
#undef LGKM0

    // epilogue: C/D layout col=lane&15, row=(lane>>4)*4+reg  [m89-verified]
    const int crow0 = bm * 256 + wm * 128;
    const int ccol0 = bn * 256 + wn * 64;
    #pragma unroll
    for (int ni = 0; ni < 4; ++ni) {
        int col = ccol0 + ni * 16 + lr;
        float bv = bias[col];
        #pragma unroll
        for (int mi = 0; mi < 8; ++mi) {
            int rbase = crow0 + mi * 16 + lk * 4;
            #pragma unroll
            for (int j = 0; j < 4; ++j) {
                C[(size_t)(rbase + j) * N_DIM + col] = acc[mi][ni][j] + bv;
            }
        }
    }
}

// ---------- fallback (ws too small): fp32 LDS-tiled, correct but slow ----------
__global__ __launch_bounds__(256)
void gemm_fallback(const float* __restrict__ X, const float* __restrict__ W,
                   const float* __restrict__ scale, const float* __restrict__ bias,
                   float* __restrict__ C) {
    int bm = blockIdx.x % (M_DIM / 64);
    int bn = blockIdx.x / (M_DIM / 64);
    __shared__ float sA[64][33];
    __shared__ float sB[64][33];
    int t = threadIdx.x;
    int tx = t & 15, ty = t >> 4;
    float acc[4][4] = {};
    for (int kt = 0; kt < K_DIM / 32; ++kt) {
        float s = scale[(bn >> 1) * (K_DIM / 128) + (kt >> 2)];
        #pragma unroll
        for (int i = 0; i < 8; ++i) {
            int idx = t + i * 256;
            int r = idx >> 5, c = idx & 31;
            sA[r][c] = X[(size_t)(bm * 64 + r) * K_DIM + kt * 32 + c];
            sB[r][c] = W[(size_t)(bn * 64 + r) * K_DIM + kt * 32 + c] * s;
        }
        __syncthreads();
        #pragma unroll
        for (int k = 0; k < 32; ++k) {
            float a[4], b[4];
            #pragma unroll
            for (int i = 0; i < 4; ++i) a[i] = sA[ty * 4 + i][k];
            #pragma unroll
            for (int j = 0; j < 4; ++j) b[j] = sB[tx * 4 + j][k];
            #pragma unroll
            for (int i = 0; i < 4; ++i)
                #pragma unroll
                for (int j = 0; j < 4; ++j) acc[i][j] += a[i] * b[j];
        }
        __syncthreads();
    }
    #pragma unroll
    for (int i = 0; i < 4; ++i)
        #pragma unroll
        for (int j = 0; j < 4; ++j) {
            int row = bm * 64 + ty * 4 + i;
            int col = bn * 64 + tx * 4 + j;
            C[(size_t)row * N_DIM + col] = acc[i][j] + bias[col];
        }
}

extern "C" void kernel_launch(void* const* d_in, const int* in_sizes, int n_in,
                              void* d_out, int out_size, void* d_ws, size_t ws_size,
                              hipStream_t stream) {
    const float* x     = (const float*)d_in[0];   // [2,2048,4096]
    const float* wgt   = (const float*)d_in[1];   // [16384,4096]
    const float* scale = (const float*)d_in[2];   // [128,32]
    const float* bias  = (const float*)d_in[3];   // [16384]
    float* out = (float*)d_out;                   // [2,2048,16384]

    const size_t need = ((size_t)M_DIM * K_DIM + (size_t)N_DIM * K_DIM) * sizeof(__hip_bfloat16);
    if (ws_size >= need) {
        __hip_bfloat16* xbf = (__hip_bfloat16*)d_ws;
        __hip_bfloat16* wbf = xbf + (size_t)M_DIM * K_DIM;
        cvt_x_kernel<<<2048, 256, 0, stream>>>(x, xbf, M_DIM * K_DIM / 8);
        dequant_w_kernel<<<4096, 256, 0, stream>>>(wgt, scale, wbf);
        gemm_bf16_kernel<<<(M_DIM / 256) * (N_DIM / 256), 512, 0, stream>>>(xbf, wbf, bias, out);
    } else {
        gemm_fallback<<<(M_DIM / 64) * (N_DIM / 64), 256, 0, stream>>>(x, wgt, scale, bias, out);
    }
}